// Round 8
// baseline (192.155 us; speedup 1.0000x reference)
//
#include <hip/hip_runtime.h>

// HistLoss: per-channel histogram matching + MSE loss.
// C=64, H=W=512, HW=262144, NBINS=256, STRENGTH=100.
//
// R8: balance experiment. Fixed harness floor ~110us (measured: total minus
// kernel-sum is constant across R1-R7); controllable kernel time ~80us.
// pass1 53us with all pipes <25% busy at exactly 2x1024-thr blocks/CU =>
// suspect fill/drain imbalance. Now 1024 blocks x 512 thr (4 blocks/CU,
// LDS 34.5KB, still 32 waves/CU) for finer-grained scheduling; histJ
// 64x64 x 256thr for the same reason. Math identical to R6/R7:
//   pass1: I-bucket LDS stats, packed u32 (count low12 | 2^28-fx sum high20),
//          per-block partials + qtot quarter totals; J minmax; nI/nJ; Q_c.
//   histJ: per-channel 256-bin masked hist of J -> per-block partials.
//   closs: 4 blocks/channel: hisPart reduce + serial f32 cumsum (ref
//          rounding), analytic arithmetic-series remap, f64 atomic,
//          done-counter writes out.
// Bucket-mean pairing stands in for exact within-bucket ranks (absmax 0.0
// in R3-R7; threshold 2.9e-6).

#define CN    64
#define HWN   262144
#define NB    256
#define NBUK  8192
#define NBLK  16
#define BPIX  (HWN/NBLK)          // 16384 pixels per pass1 block
#define PT    512                 // pass1 threads
#define XB    64                  // histJ blocks per channel
#define QBUK  (NBUK/4)            // 2048 buckets per closs block
#define FXS2  268435456.0f        // 2^28 fixed-point scale for sum(v-center)
#define FXSI2 (1.0/268435456.0)

__global__ __launch_bounds__(PT) void k_pass1(
    const float* __restrict__ I, const float* __restrict__ J,
    const int* __restrict__ mI, const int* __restrict__ mJ,
    unsigned* __restrict__ pc, unsigned* __restrict__ qtot,
    unsigned* __restrict__ mnp, unsigned* __restrict__ mxp,
    unsigned* __restrict__ cp, double* __restrict__ qp)
{
  const int c = blockIdx.y, q = blockIdx.x, tid = threadIdx.x;
  const int bid = c*NBLK + q;
  const int wid = tid >> 6, lane = tid & 63;
  __shared__ unsigned buk[NBUK];                    // packed (fx<<12)+count
  __shared__ unsigned sred[PT];
  __shared__ double   dred[PT/64];
  __shared__ unsigned umn[PT/64], umx[PT/64], uci[PT/64], ucj[PT/64];
  for(int i = tid; i < NBUK; i += PT) buk[i] = 0u;
  __syncthreads();

  const float4* Ic  = (const float4*)(I + (size_t)c*HWN + (size_t)q*BPIX);
  const float4* Jc  = (const float4*)(J + (size_t)c*HWN + (size_t)q*BPIX);
  const int4*   MiQ = (const int4*)(mI + (size_t)q*BPIX);
  const int4*   MjQ = (const int4*)(mJ + (size_t)q*BPIX);

  float qacc = 0.0f;
  unsigned ci = 0, cj = 0;
  unsigned mn = 0x7F800000u, mx = 0u;
  #pragma unroll 4
  for(int it = 0; it < BPIX/(PT*4); ++it){          // 8 iters, merged I+J
    int idx = it*PT + tid;
    float4 vi4 = Ic[idx];  int4 mi4 = MiQ[idx];     // 4 independent 16B loads
    float4 vj4 = Jc[idx];  int4 mj4 = MjQ[idx];     // issued before any use
    {
      float vv[4] = {vi4.x,vi4.y,vi4.z,vi4.w};
      int   mm[4] = {mi4.x,mi4.y,mi4.z,mi4.w};
      #pragma unroll
      for(int e = 0; e < 4; e++){
        if(mm[e] > 0){
          float v = vv[e];
          int k = (int)(v * (float)NBUK);           // pow2 scale: exact, monotone
          if(k > NBUK-1) k = NBUK-1;
          float dv = v - ((float)k + 0.5f) * (1.0f/(float)NBUK);
          int fx = (int)rintf(dv * FXS2);           // |fx| <= 16384
          atomicAdd(&buk[k], ((unsigned)fx << 12) + 1u);
          qacc += dv*dv;
          ci++;
        }
      }
    }
    {
      if(mj4.x>0){unsigned u=__float_as_uint(vj4.x); mn=min(mn,u); mx=max(mx,u); cj++;}
      if(mj4.y>0){unsigned u=__float_as_uint(vj4.y); mn=min(mn,u); mx=max(mx,u); cj++;}
      if(mj4.z>0){unsigned u=__float_as_uint(vj4.z); mn=min(mn,u); mx=max(mx,u); cj++;}
      if(mj4.w>0){unsigned u=__float_as_uint(vj4.w); mn=min(mn,u); mx=max(mx,u); cj++;}
    }
  }
  __syncthreads();                                   // LDS atomics complete
  { unsigned* pcb = pc + (size_t)bid * NBUK;
    for(int i = tid; i < NBUK; i += PT) pcb[i] = buk[i]; }

  // per-quarter count totals: thread t sums buk[t*16..t*16+15] (one quarter),
  // 128 threads per quarter, segmented reduce
  { unsigned csum = 0;
    #pragma unroll
    for(int j = 0; j < 16; j++) csum += buk[tid*16 + j] & 0xFFFu;
    sred[tid] = csum; __syncthreads();
    for(int s = 64; s > 0; s >>= 1){
      if((tid & 127) < s) sred[tid] += sred[tid + s];
      __syncthreads();
    }
    if((tid & 127) == 0) qtot[bid*4 + (tid >> 7)] = sred[tid];
  }

  double qd = (double)qacc;
  for(int o = 32; o > 0; o >>= 1){
    qd += __shfl_down(qd, o, 64);
    mn  = min(mn, (unsigned)__shfl_down(mn, o, 64));
    mx  = max(mx, (unsigned)__shfl_down(mx, o, 64));
    ci += __shfl_down(ci, o, 64);
    cj += __shfl_down(cj, o, 64);
  }
  if(lane == 0){ dred[wid]=qd; umn[wid]=mn; umx[wid]=mx; uci[wid]=ci; ucj[wid]=cj; }
  __syncthreads();
  if(tid == 0){
    double t = 0.0; unsigned amn=0x7F800000u, amx=0u, aci=0, acj=0;
    for(int w = 0; w < PT/64; w++){
      t += dred[w];
      amn = min(amn, umn[w]); amx = max(amx, umx[w]);
      aci += uci[w]; acj += ucj[w];
    }
    qp[bid] = t;
    mnp[bid] = amn; mxp[bid] = amx;
    if(c == 0){ cp[2*q] = aci; cp[2*q+1] = acj; }
  }
}

__global__ __launch_bounds__(256) void k_histJ(
    const float* __restrict__ J, const int* __restrict__ mJ,
    const unsigned* __restrict__ mnp, const unsigned* __restrict__ mxp,
    unsigned* __restrict__ hisPart, double* __restrict__ lossacc,
    unsigned* __restrict__ donecnt)
{
  const int c = blockIdx.y, xb = blockIdx.x, tid = threadIdx.x;
  if(c == 0 && xb == 0 && tid == 0){ *lossacc = 0.0; *donecnt = 0u; } // for k_closs
  unsigned mnu = 0x7F800000u, mxu = 0u;
  #pragma unroll
  for(int qi = 0; qi < NBLK; qi++){
    mnu = min(mnu, mnp[c*NBLK + qi]);
    mxu = max(mxu, mxp[c*NBLK + qi]);
  }
  float mnv = __uint_as_float(mnu);
  float den = fmaxf((__uint_as_float(mxu) - mnv) / (float)NB, 1e-12f);
  __shared__ unsigned h[NB];
  h[tid] = 0u;
  __syncthreads();
  const int SLICE = HWN/XB;                          // 4096 pixels per block
  const float4* Jc = (const float4*)(J + (size_t)c*HWN + (size_t)xb*SLICE);
  const int4*   Mj = (const int4*)(mJ + (size_t)xb*SLICE);
  #pragma unroll
  for(int it = 0; it < SLICE/1024; ++it){            // 4 iters
    int idx = it*256 + tid;
    float4 v4 = Jc[idx]; int4 m4 = Mj[idx];
    float vv[4] = {v4.x,v4.y,v4.z,v4.w};
    int   mm[4] = {m4.x,m4.y,m4.z,m4.w};
    #pragma unroll
    for(int e = 0; e < 4; e++){
      if(mm[e] > 0){
        float bf = floorf((vv[e] - mnv) / den);      // replicate ref: divide, floor, clip
        bf = fminf(fmaxf(bf, 0.0f), 255.0f);
        atomicAdd(&h[(int)bf], 1u);
      }
    }
  }
  __syncthreads();
  hisPart[((size_t)c*XB + xb)*NB + tid] = h[tid];
}

__global__ __launch_bounds__(1024) void k_closs(
    const unsigned* __restrict__ pc, const unsigned* __restrict__ qtot,
    const unsigned* __restrict__ hisPart,
    const unsigned* __restrict__ mnp, const unsigned* __restrict__ mxp,
    const unsigned* __restrict__ cp, const double* __restrict__ qp,
    double* __restrict__ lossacc, unsigned* __restrict__ donecnt,
    float* __restrict__ out)
{
  const int c = blockIdx.x >> 2, qt = blockIdx.x & 3, tid = threadIdx.x;
  const int wid = tid >> 6, lane = tid & 63;
  __shared__ float cs[NB], hs[NB];
  __shared__ unsigned hsum[NB];
  __shared__ unsigned qsh[NBLK*4];
  __shared__ unsigned wsum[16];
  __shared__ double red[16];
  __shared__ float sh_mn, sh_st;
  __shared__ unsigned sh_base;

  if(tid < NB){
    unsigned hr = 0u;
    for(int xb = 0; xb < XB; xb++) hr += hisPart[((size_t)c*XB + xb)*NB + tid];
    hsum[tid] = hr;
  } else if(tid < NB + NBLK*4){
    int k = tid - NB;                                // 16 slices x 4 quarters
    qsh[k] = qtot[(c*NBLK + (k >> 2))*4 + (k & 3)];
  }
  __syncthreads();
  if(tid == 0){
    unsigned ciw = 0, cjw = 0;
    for(int qi = 0; qi < NBLK; qi++){ ciw += cp[2*qi]; cjw += cp[2*qi+1]; }
    float ratio = (float)ciw / (float)cjw;           // nI/nJ in f32, as in ref
    float cum = 0.0f;
    for(int b = 0; b < NB; b++){
      float hh = (float)hsum[b] * ratio;
      hs[b] = hh;
      cum += hh;                                     // sequential f32 == ref rounding
      cs[b] = cum;
    }
    unsigned mnu = 0x7F800000u, mxu = 0u;
    for(int qi = 0; qi < NBLK; qi++){ mnu = min(mnu, mnp[c*NBLK+qi]); mxu = max(mxu, mxp[c*NBLK+qi]); }
    sh_mn = __uint_as_float(mnu);
    sh_st = (__uint_as_float(mxu) - sh_mn) / (float)NB;
    unsigned base = 0;
    for(int s = 0; s < NBLK; s++)
      for(int q2 = 0; q2 < qt; q2++) base += qsh[s*4 + q2];
    sh_base = base;
  }
  __syncthreads();

  // own 2 buckets: b0 = qt*QBUK + tid*2 (+0,+1)
  unsigned  kk[2] = {0,0};
  long long ss[2] = {0,0};
  for(int sl = 0; sl < NBLK; sl++){
    const uint2* pcb = (const uint2*)(pc + (size_t)(c*NBLK + sl)*NBUK + qt*QBUK) + tid;
    uint2 w = *pcb;
    kk[0] += w.x & 0xFFFu;  ss[0] += (int)w.x >> 12; // arithmetic shift: sign-extend sum
    kk[1] += w.y & 0xFFFu;  ss[1] += (int)w.y >> 12;
  }
  unsigned run = kk[0] + kk[1];
  unsigned v = run;                                  // wave inclusive scan
  for(int o = 1; o < 64; o <<= 1){
    unsigned t = __shfl_up(v, o, 64);
    if(lane >= o) v += t;
  }
  if(lane == 63) wsum[wid] = v;
  __syncthreads();
  unsigned wbase = 0;
  for(int w = 0; w < wid; w++) wbase += wsum[w];
  unsigned texcl = sh_base + wbase + (v - run);

  float  mnvf = sh_mn, stepf = sh_st;
  double mnvd = (double)mnvf, stepd = (double)stepf;

  float rf0 = (float)(texcl + 1u);                   // left-search start bin
  int lo = 0, hi = NB;
  while(lo < hi){ int mid = (lo + hi) >> 1; if(cs[mid] < rf0) lo = mid + 1; else hi = mid; }
  int bin = (lo > NB-1) ? NB-1 : lo;

  double acc = 0.0;
  unsigned r = texcl;
  #pragma unroll
  for(int j = 0; j < 2; j++){
    unsigned k = kk[j];
    if(k == 0) continue;
    unsigned ra = r + 1u, rb = r + k; r = rb;
    double sval = 0.0;
    while(ra <= rb){
      while(bin < NB-1 && cs[bin] < (float)ra) bin++;
      float csb = cs[bin], hsb = hs[bin];
      unsigned re = (bin == NB-1) ? rb : min(rb, (unsigned)floorf(csb));
      double lovd = (double)csb - (double)hsb;
      double den2 = fmax((double)hsb, 1e-12);
      double ra_d = (double)ra, re_d = (double)re, nn = (double)(re - ra + 1u);
      double rta = (ra_d - lovd)/den2, rtb = (re_d - lovd)/den2;
      if(hsb > 0.0f && rta >= 0.0 && rtb <= 1.0){
        double sumr = 0.5*(ra_d + re_d)*nn;          // arithmetic series of ranks
        sval += nn*(mnvd + (double)bin*stepd) + stepd*(sumr - nn*lovd)/den2;
      } else {                                       // exact per-rank f32 fallback
        for(unsigned rr = ra; rr <= re; rr++){
          float rf = (float)rr;
          float lov = csb - hsb;
          float rt = (rf - lov) / fmaxf(hsb, 1e-12f);
          rt = fminf(fmaxf(rt, 0.0f), 1.0f);
          sval += (double)(mnvf + ((float)bin + rt)*stepf);
        }
      }
      ra = re + 1u;
    }
    double kb   = (double)k;
    double cb   = ((double)(qt*QBUK + tid*2 + j) + 0.5) * (1.0/(double)NBUK);
    double vbar = sval/kb - cb;                      // mean(val) - bucket center
    double S    = (double)ss[j] * FXSI2;             // sum(v - center)
    acc += kb*vbar*vbar - 2.0*vbar*S;
  }
  if(qt == 0 && tid == 0){                           // Q_c = sum(v-center)^2, once/channel
    double qsum = 0.0;
    for(int qi = 0; qi < NBLK; qi++) qsum += qp[c*NBLK + qi];
    acc += qsum;
  }
  for(int o = 32; o > 0; o >>= 1) acc += __shfl_down(acc, o, 64);
  if(lane == 0) red[wid] = acc;
  __syncthreads();
  if(tid == 0){
    double t = 0.0;
    for(int w = 0; w < 16; w++) t += red[w];
    atomicAdd(lossacc, t);
    __threadfence();
    unsigned old = atomicAdd(donecnt, 1u);
    if(old == (unsigned)(CN*4 - 1)){                 // last block finalizes
      double tot = atomicAdd(lossacc, 0.0);          // coherent read
      out[0] = (float)(tot * (100.0 / (double)((size_t)CN * HWN)));
    }
  }
}

extern "C" void kernel_launch(void* const* d_in, const int* in_sizes, int n_in,
                              void* d_out, int out_size, void* d_ws, size_t ws_size,
                              hipStream_t stream){
  const float* I  = (const float*)d_in[0];
  const float* J  = (const float*)d_in[1];
  const int*   mI = (const int*)d_in[2];
  const int*   mJ = (const int*)d_in[3];
  float* out = (float*)d_out;

  char* base = (char*)d_ws;
  size_t pcB = (size_t)CN * NBLK * NBUK * sizeof(unsigned);      // 32 MB
  size_t hpB = (size_t)CN * XB * NB * sizeof(unsigned);          // 4 MB
  size_t qtB = (size_t)CN * NBLK * 4 * sizeof(unsigned);         // 16 KB
  unsigned* pc      = (unsigned*)base;
  unsigned* hisPart = (unsigned*)(base + pcB);
  unsigned* qtot    = (unsigned*)(base + pcB + hpB);
  char* p = base + pcB + hpB + qtB;
  double*   qp      = (double*)p;   p += (size_t)CN*NBLK*sizeof(double);
  double*   lossacc = (double*)p;   p += sizeof(double);
  unsigned* mnp     = (unsigned*)p; p += (size_t)CN*NBLK*sizeof(unsigned);
  unsigned* mxp     = (unsigned*)p; p += (size_t)CN*NBLK*sizeof(unsigned);
  unsigned* cp      = (unsigned*)p; p += 2*NBLK*sizeof(unsigned);
  unsigned* donecnt = (unsigned*)p;

  k_pass1<<<dim3(NBLK, CN), PT, 0, stream>>>(I, J, mI, mJ, pc, qtot, mnp, mxp, cp, qp);
  k_histJ<<<dim3(XB, CN), 256, 0, stream>>>(J, mJ, mnp, mxp, hisPart, lossacc, donecnt);
  k_closs<<<CN*4, 1024, 0, stream>>>(pc, qtot, hisPart, mnp, mxp, cp, qp, lossacc, donecnt, out);
}

// Round 9
// 187.062 us; speedup vs baseline: 1.0272x; 1.0272x over previous
//
#include <hip/hip_runtime.h>

// HistLoss: per-channel histogram matching + MSE loss.
// C=64, H=W=512, HW=262144, NBINS=256, STRENGTH=100.
//
// R9: pass1 MLP fix via explicit register double-buffer. Evidence: pass1
// pinned at 52-56us across R6/R7/R8 with VGPR_Count 24-32 — the compiler
// register-minimizes, capping outstanding 16B loads at ~4/wave; at ~600-900cy
// L3/HBM latency that predicts the measured 0.52 pixels/cyc/CU exactly.
// Now: 4 batches of 2x(I,mI,J,mJ) groups per thread; batch b+1's 8
// independent loads issue before batch b is processed (explicit arrays,
// full unroll, ~90 VGPR, __launch_bounds__(512,4) caps at 128).
// histJ/closs and ALL math bit-identical to R8:
//   pass1: I-bucket LDS stats, packed u32 (count low12 | 2^28-fx sum high20),
//          per-block partials + qtot quarter totals; J minmax; nI/nJ; Q_c.
//   histJ: per-channel 256-bin masked hist of J -> per-block partials.
//   closs: 4 blocks/channel: hisPart reduce + serial f32 cumsum (ref
//          rounding), analytic arithmetic-series remap, f64 atomic,
//          done-counter writes out.
// Bucket-mean pairing stands in for exact within-bucket ranks (absmax 0.0
// in R3-R8; threshold 2.9e-6).

#define CN    64
#define HWN   262144
#define NB    256
#define NBUK  8192
#define NBLK  16
#define BPIX  (HWN/NBLK)          // 16384 pixels per pass1 block
#define PT    512                 // pass1 threads
#define XB    64                  // histJ blocks per channel
#define QBUK  (NBUK/4)            // 2048 buckets per closs block
#define FXS2  268435456.0f        // 2^28 fixed-point scale for sum(v-center)
#define FXSI2 (1.0/268435456.0)

__global__ __launch_bounds__(PT, 4) void k_pass1(
    const float* __restrict__ I, const float* __restrict__ J,
    const int* __restrict__ mI, const int* __restrict__ mJ,
    unsigned* __restrict__ pc, unsigned* __restrict__ qtot,
    unsigned* __restrict__ mnp, unsigned* __restrict__ mxp,
    unsigned* __restrict__ cp, double* __restrict__ qp)
{
  const int c = blockIdx.y, q = blockIdx.x, tid = threadIdx.x;
  const int bid = c*NBLK + q;
  const int wid = tid >> 6, lane = tid & 63;
  __shared__ unsigned buk[NBUK];                    // packed (fx<<12)+count
  __shared__ unsigned sred[PT];
  __shared__ double   dred[PT/64];
  __shared__ unsigned umn[PT/64], umx[PT/64], uci[PT/64], ucj[PT/64];
  for(int i = tid; i < NBUK; i += PT) buk[i] = 0u;
  __syncthreads();

  const float4* Ic  = (const float4*)(I + (size_t)c*HWN + (size_t)q*BPIX);
  const float4* Jc  = (const float4*)(J + (size_t)c*HWN + (size_t)q*BPIX);
  const int4*   MiQ = (const int4*)(mI + (size_t)q*BPIX);
  const int4*   MjQ = (const int4*)(mJ + (size_t)q*BPIX);

  float qacc = 0.0f;
  unsigned ci = 0, cj = 0;
  unsigned mn = 0x7F800000u, mx = 0u;

  // 8 groups/thread (group g at idx g*PT+tid), 4 batches of 2 groups,
  // register double-buffer: batch b+1's loads in flight while b processes.
  float4 bi[2][2]; int4 bmi[2][2];
  float4 bj[2][2]; int4 bmj[2][2];
  #pragma unroll
  for(int g = 0; g < 2; g++){
    int idx = g*PT + tid;
    bi [0][g] = Ic[idx];  bmi[0][g] = MiQ[idx];
    bj [0][g] = Jc[idx];  bmj[0][g] = MjQ[idx];
  }
  #pragma unroll
  for(int b = 0; b < 4; b++){
    const int cur = b & 1, nxt = cur ^ 1;
    if(b < 3){
      #pragma unroll
      for(int g = 0; g < 2; g++){
        int idx = (2*(b+1) + g)*PT + tid;            // 8 loads issued up front
        bi [nxt][g] = Ic[idx];  bmi[nxt][g] = MiQ[idx];
        bj [nxt][g] = Jc[idx];  bmj[nxt][g] = MjQ[idx];
      }
    }
    #pragma unroll
    for(int g = 0; g < 2; g++){
      float4 vi4 = bi[cur][g]; int4 mi4 = bmi[cur][g];
      float4 vj4 = bj[cur][g]; int4 mj4 = bmj[cur][g];
      float vv[4] = {vi4.x,vi4.y,vi4.z,vi4.w};
      int   mm[4] = {mi4.x,mi4.y,mi4.z,mi4.w};
      #pragma unroll
      for(int e = 0; e < 4; e++){
        if(mm[e] > 0){
          float v = vv[e];
          int k = (int)(v * (float)NBUK);            // pow2 scale: exact, monotone
          if(k > NBUK-1) k = NBUK-1;
          float dv = v - ((float)k + 0.5f) * (1.0f/(float)NBUK);
          int fx = (int)rintf(dv * FXS2);            // |fx| <= 16384
          atomicAdd(&buk[k], ((unsigned)fx << 12) + 1u);
          qacc += dv*dv;
          ci++;
        }
      }
      if(mj4.x>0){unsigned u=__float_as_uint(vj4.x); mn=min(mn,u); mx=max(mx,u); cj++;}
      if(mj4.y>0){unsigned u=__float_as_uint(vj4.y); mn=min(mn,u); mx=max(mx,u); cj++;}
      if(mj4.z>0){unsigned u=__float_as_uint(vj4.z); mn=min(mn,u); mx=max(mx,u); cj++;}
      if(mj4.w>0){unsigned u=__float_as_uint(vj4.w); mn=min(mn,u); mx=max(mx,u); cj++;}
    }
  }
  __syncthreads();                                   // LDS atomics complete
  { unsigned* pcb = pc + (size_t)bid * NBUK;
    for(int i = tid; i < NBUK; i += PT) pcb[i] = buk[i]; }

  // per-quarter count totals: thread t sums buk[t*16..t*16+15] (one quarter),
  // 128 threads per quarter, segmented reduce
  { unsigned csum = 0;
    #pragma unroll
    for(int j = 0; j < 16; j++) csum += buk[tid*16 + j] & 0xFFFu;
    sred[tid] = csum; __syncthreads();
    for(int s = 64; s > 0; s >>= 1){
      if((tid & 127) < s) sred[tid] += sred[tid + s];
      __syncthreads();
    }
    if((tid & 127) == 0) qtot[bid*4 + (tid >> 7)] = sred[tid];
  }

  double qd = (double)qacc;
  for(int o = 32; o > 0; o >>= 1){
    qd += __shfl_down(qd, o, 64);
    mn  = min(mn, (unsigned)__shfl_down(mn, o, 64));
    mx  = max(mx, (unsigned)__shfl_down(mx, o, 64));
    ci += __shfl_down(ci, o, 64);
    cj += __shfl_down(cj, o, 64);
  }
  if(lane == 0){ dred[wid]=qd; umn[wid]=mn; umx[wid]=mx; uci[wid]=ci; ucj[wid]=cj; }
  __syncthreads();
  if(tid == 0){
    double t = 0.0; unsigned amn=0x7F800000u, amx=0u, aci=0, acj=0;
    for(int w = 0; w < PT/64; w++){
      t += dred[w];
      amn = min(amn, umn[w]); amx = max(amx, umx[w]);
      aci += uci[w]; acj += ucj[w];
    }
    qp[bid] = t;
    mnp[bid] = amn; mxp[bid] = amx;
    if(c == 0){ cp[2*q] = aci; cp[2*q+1] = acj; }
  }
}

__global__ __launch_bounds__(256) void k_histJ(
    const float* __restrict__ J, const int* __restrict__ mJ,
    const unsigned* __restrict__ mnp, const unsigned* __restrict__ mxp,
    unsigned* __restrict__ hisPart, double* __restrict__ lossacc,
    unsigned* __restrict__ donecnt)
{
  const int c = blockIdx.y, xb = blockIdx.x, tid = threadIdx.x;
  if(c == 0 && xb == 0 && tid == 0){ *lossacc = 0.0; *donecnt = 0u; } // for k_closs
  unsigned mnu = 0x7F800000u, mxu = 0u;
  #pragma unroll
  for(int qi = 0; qi < NBLK; qi++){
    mnu = min(mnu, mnp[c*NBLK + qi]);
    mxu = max(mxu, mxp[c*NBLK + qi]);
  }
  float mnv = __uint_as_float(mnu);
  float den = fmaxf((__uint_as_float(mxu) - mnv) / (float)NB, 1e-12f);
  __shared__ unsigned h[NB];
  h[tid] = 0u;
  __syncthreads();
  const int SLICE = HWN/XB;                          // 4096 pixels per block
  const float4* Jc = (const float4*)(J + (size_t)c*HWN + (size_t)xb*SLICE);
  const int4*   Mj = (const int4*)(mJ + (size_t)xb*SLICE);
  #pragma unroll
  for(int it = 0; it < SLICE/1024; ++it){            // 4 iters
    int idx = it*256 + tid;
    float4 v4 = Jc[idx]; int4 m4 = Mj[idx];
    float vv[4] = {v4.x,v4.y,v4.z,v4.w};
    int   mm[4] = {m4.x,m4.y,m4.z,m4.w};
    #pragma unroll
    for(int e = 0; e < 4; e++){
      if(mm[e] > 0){
        float bf = floorf((vv[e] - mnv) / den);      // replicate ref: divide, floor, clip
        bf = fminf(fmaxf(bf, 0.0f), 255.0f);
        atomicAdd(&h[(int)bf], 1u);
      }
    }
  }
  __syncthreads();
  hisPart[((size_t)c*XB + xb)*NB + tid] = h[tid];
}

__global__ __launch_bounds__(1024) void k_closs(
    const unsigned* __restrict__ pc, const unsigned* __restrict__ qtot,
    const unsigned* __restrict__ hisPart,
    const unsigned* __restrict__ mnp, const unsigned* __restrict__ mxp,
    const unsigned* __restrict__ cp, const double* __restrict__ qp,
    double* __restrict__ lossacc, unsigned* __restrict__ donecnt,
    float* __restrict__ out)
{
  const int c = blockIdx.x >> 2, qt = blockIdx.x & 3, tid = threadIdx.x;
  const int wid = tid >> 6, lane = tid & 63;
  __shared__ float cs[NB], hs[NB];
  __shared__ unsigned hsum[NB];
  __shared__ unsigned qsh[NBLK*4];
  __shared__ unsigned wsum[16];
  __shared__ double red[16];
  __shared__ float sh_mn, sh_st;
  __shared__ unsigned sh_base;

  if(tid < NB){
    unsigned hr = 0u;
    for(int xb = 0; xb < XB; xb++) hr += hisPart[((size_t)c*XB + xb)*NB + tid];
    hsum[tid] = hr;
  } else if(tid < NB + NBLK*4){
    int k = tid - NB;                                // 16 slices x 4 quarters
    qsh[k] = qtot[(c*NBLK + (k >> 2))*4 + (k & 3)];
  }
  __syncthreads();
  if(tid == 0){
    unsigned ciw = 0, cjw = 0;
    for(int qi = 0; qi < NBLK; qi++){ ciw += cp[2*qi]; cjw += cp[2*qi+1]; }
    float ratio = (float)ciw / (float)cjw;           // nI/nJ in f32, as in ref
    float cum = 0.0f;
    for(int b = 0; b < NB; b++){
      float hh = (float)hsum[b] * ratio;
      hs[b] = hh;
      cum += hh;                                     // sequential f32 == ref rounding
      cs[b] = cum;
    }
    unsigned mnu = 0x7F800000u, mxu = 0u;
    for(int qi = 0; qi < NBLK; qi++){ mnu = min(mnu, mnp[c*NBLK+qi]); mxu = max(mxu, mxp[c*NBLK+qi]); }
    sh_mn = __uint_as_float(mnu);
    sh_st = (__uint_as_float(mxu) - sh_mn) / (float)NB;
    unsigned base = 0;
    for(int s = 0; s < NBLK; s++)
      for(int q2 = 0; q2 < qt; q2++) base += qsh[s*4 + q2];
    sh_base = base;
  }
  __syncthreads();

  // own 2 buckets: b0 = qt*QBUK + tid*2 (+0,+1)
  unsigned  kk[2] = {0,0};
  long long ss[2] = {0,0};
  for(int sl = 0; sl < NBLK; sl++){
    const uint2* pcb = (const uint2*)(pc + (size_t)(c*NBLK + sl)*NBUK + qt*QBUK) + tid;
    uint2 w = *pcb;
    kk[0] += w.x & 0xFFFu;  ss[0] += (int)w.x >> 12; // arithmetic shift: sign-extend sum
    kk[1] += w.y & 0xFFFu;  ss[1] += (int)w.y >> 12;
  }
  unsigned run = kk[0] + kk[1];
  unsigned v = run;                                  // wave inclusive scan
  for(int o = 1; o < 64; o <<= 1){
    unsigned t = __shfl_up(v, o, 64);
    if(lane >= o) v += t;
  }
  if(lane == 63) wsum[wid] = v;
  __syncthreads();
  unsigned wbase = 0;
  for(int w = 0; w < wid; w++) wbase += wsum[w];
  unsigned texcl = sh_base + wbase + (v - run);

  float  mnvf = sh_mn, stepf = sh_st;
  double mnvd = (double)mnvf, stepd = (double)stepf;

  float rf0 = (float)(texcl + 1u);                   // left-search start bin
  int lo = 0, hi = NB;
  while(lo < hi){ int mid = (lo + hi) >> 1; if(cs[mid] < rf0) lo = mid + 1; else hi = mid; }
  int bin = (lo > NB-1) ? NB-1 : lo;

  double acc = 0.0;
  unsigned r = texcl;
  #pragma unroll
  for(int j = 0; j < 2; j++){
    unsigned k = kk[j];
    if(k == 0) continue;
    unsigned ra = r + 1u, rb = r + k; r = rb;
    double sval = 0.0;
    while(ra <= rb){
      while(bin < NB-1 && cs[bin] < (float)ra) bin++;
      float csb = cs[bin], hsb = hs[bin];
      unsigned re = (bin == NB-1) ? rb : min(rb, (unsigned)floorf(csb));
      double lovd = (double)csb - (double)hsb;
      double den2 = fmax((double)hsb, 1e-12);
      double ra_d = (double)ra, re_d = (double)re, nn = (double)(re - ra + 1u);
      double rta = (ra_d - lovd)/den2, rtb = (re_d - lovd)/den2;
      if(hsb > 0.0f && rta >= 0.0 && rtb <= 1.0){
        double sumr = 0.5*(ra_d + re_d)*nn;          // arithmetic series of ranks
        sval += nn*(mnvd + (double)bin*stepd) + stepd*(sumr - nn*lovd)/den2;
      } else {                                       // exact per-rank f32 fallback
        for(unsigned rr = ra; rr <= re; rr++){
          float rf = (float)rr;
          float lov = csb - hsb;
          float rt = (rf - lov) / fmaxf(hsb, 1e-12f);
          rt = fminf(fmaxf(rt, 0.0f), 1.0f);
          sval += (double)(mnvf + ((float)bin + rt)*stepf);
        }
      }
      ra = re + 1u;
    }
    double kb   = (double)k;
    double cb   = ((double)(qt*QBUK + tid*2 + j) + 0.5) * (1.0/(double)NBUK);
    double vbar = sval/kb - cb;                      // mean(val) - bucket center
    double S    = (double)ss[j] * FXSI2;             // sum(v - center)
    acc += kb*vbar*vbar - 2.0*vbar*S;
  }
  if(qt == 0 && tid == 0){                           // Q_c = sum(v-center)^2, once/channel
    double qsum = 0.0;
    for(int qi = 0; qi < NBLK; qi++) qsum += qp[c*NBLK + qi];
    acc += qsum;
  }
  for(int o = 32; o > 0; o >>= 1) acc += __shfl_down(acc, o, 64);
  if(lane == 0) red[wid] = acc;
  __syncthreads();
  if(tid == 0){
    double t = 0.0;
    for(int w = 0; w < 16; w++) t += red[w];
    atomicAdd(lossacc, t);
    __threadfence();
    unsigned old = atomicAdd(donecnt, 1u);
    if(old == (unsigned)(CN*4 - 1)){                 // last block finalizes
      double tot = atomicAdd(lossacc, 0.0);          // coherent read
      out[0] = (float)(tot * (100.0 / (double)((size_t)CN * HWN)));
    }
  }
}

extern "C" void kernel_launch(void* const* d_in, const int* in_sizes, int n_in,
                              void* d_out, int out_size, void* d_ws, size_t ws_size,
                              hipStream_t stream){
  const float* I  = (const float*)d_in[0];
  const float* J  = (const float*)d_in[1];
  const int*   mI = (const int*)d_in[2];
  const int*   mJ = (const int*)d_in[3];
  float* out = (float*)d_out;

  char* base = (char*)d_ws;
  size_t pcB = (size_t)CN * NBLK * NBUK * sizeof(unsigned);      // 32 MB
  size_t hpB = (size_t)CN * XB * NB * sizeof(unsigned);          // 4 MB
  size_t qtB = (size_t)CN * NBLK * 4 * sizeof(unsigned);         // 16 KB
  unsigned* pc      = (unsigned*)base;
  unsigned* hisPart = (unsigned*)(base + pcB);
  unsigned* qtot    = (unsigned*)(base + pcB + hpB);
  char* p = base + pcB + hpB + qtB;
  double*   qp      = (double*)p;   p += (size_t)CN*NBLK*sizeof(double);
  double*   lossacc = (double*)p;   p += sizeof(double);
  unsigned* mnp     = (unsigned*)p; p += (size_t)CN*NBLK*sizeof(unsigned);
  unsigned* mxp     = (unsigned*)p; p += (size_t)CN*NBLK*sizeof(unsigned);
  unsigned* cp      = (unsigned*)p; p += 2*NBLK*sizeof(unsigned);
  unsigned* donecnt = (unsigned*)p;

  k_pass1<<<dim3(NBLK, CN), PT, 0, stream>>>(I, J, mI, mJ, pc, qtot, mnp, mxp, cp, qp);
  k_histJ<<<dim3(XB, CN), 256, 0, stream>>>(J, mJ, mnp, mxp, hisPart, lossacc, donecnt);
  k_closs<<<CN*4, 1024, 0, stream>>>(pc, qtot, hisPart, mnp, mxp, cp, qp, lossacc, donecnt, out);
}